// Round 7
// baseline (638.313 us; speedup 1.0000x reference)
//
#include <hip/hip_runtime.h>

#define BATCH 65536

typedef float f32x4 __attribute__((ext_vector_type(4)));
typedef _Float16 f16x8 __attribute__((ext_vector_type(8)));

__device__ __forceinline__ float act_f(float x, float a0, float a1, float a2,
                                       float a3, float a4) {
  float ax = fabsf(x);
  float e = __builtin_amdgcn_exp2f(ax * -2.8853900817779268f);
  float th = (1.0f - e) * __builtin_amdgcn_rcpf(1.0f + e);
  th = copysignf(th, x);
  float arg = fmaf(a1, x, a2);
  float rev = arg * 0.15915494309189535f;
  rev -= floorf(rev);
  float s = __builtin_amdgcn_sinf(rev);
  return fmaf(a3, x, fmaf(a0 * th, s, a4));
}

// split + transpose weights: W[K][N] fp32 -> Wt_hi/lo[N][K] fp16.
// i indexes the OUTPUT (n,k): writes coalesced, reads strided (reads are
// cache-absorbed; scattered 2B writes were 64x write-amplified).
__global__ __launch_bounds__(256) void splitT_k(const float* __restrict__ W,
                                                _Float16* __restrict__ hi,
                                                _Float16* __restrict__ lo,
                                                int K, int N) {
  const int i = blockIdx.x * 256 + threadIdx.x;
  if (i >= K * N) return;
  const int n = i / K, k = i % K;
  const float w = W[(size_t)k * N + n];
  const _Float16 h = (_Float16)w;
  hi[i] = h;
  lo[i] = (_Float16)(w - (float)h);
}

__device__ __forceinline__ f32x4 mfma3(f16x8 ah, f16x8 al, f16x8 bh, f16x8 bl,
                                       f32x4 c) {
  c = __builtin_amdgcn_mfma_f32_16x16x32_f16(ah, bh, c, 0, 0, 0);
  c = __builtin_amdgcn_mfma_f32_16x16x32_f16(ah, bl, c, 0, 0, 0);
  c = __builtin_amdgcn_mfma_f32_16x16x32_f16(al, bh, c, 0, 0, 0);
  return c;
}

// Fully fused 3-layer MLP + softmax. One block = 32 batch rows, 512 threads
// (8 waves). LDS = 65.2 KB -> 2 INDEPENDENT blocks/CU (16 waves/CU,
// 4/SIMD): co-resident blocks fill each other's barrier drains and memory
// waits (the r0 multi-kernel GEMMs' 32% MfmaUtil came from exactly this).
// Phase 2 is kt-outer with all of h2 in registers (acc2[4][2]), so h2
// overwrites h1's LDS region and the per-kt MFMA cluster is 24 (vs r3's 6 -
// r3's regression isolated to cluster size, not residency).
// 3-product fp16 hi/lo compensation; per-element MFMA sequence and k-order
// identical to the verified pipeline (absmax bit-identical).
__global__ __launch_bounds__(512, 4) void fused_mlp(
    const float* __restrict__ data, const _Float16* __restrict__ w1h,
    const _Float16* __restrict__ w1l, const _Float16* __restrict__ w2h,
    const _Float16* __restrict__ w2l, const _Float16* __restrict__ w3h,
    const _Float16* __restrict__ w3l, const float* __restrict__ b1,
    const float* __restrict__ p1, const float* __restrict__ b2,
    const float* __restrict__ p2, const float* __restrict__ b3,
    const float* __restrict__ p3, float* __restrict__ out) {
  // region A: [0,32768) hi plane, [32768,65536) lo plane (h1 then h2),
  //           32 rows x 1024 B (512 fp16 cols), XOR-swizzled.
  // scratch:  [65536,66560) red[8][32], [66560,66688) rowred[32]
  __shared__ __align__(16) char smem[66688];
  float* const red = (float*)(smem + 65536);
  float* const rowred = (float*)(smem + 66560);

  const int tid = threadIdx.x;
  const int wv = tid >> 6;
  const int lane = tid & 63;
  const int m16 = lane & 15;
  const int quad = lane >> 4;
  const int kq = quad * 8;
  const int row0 = blockIdx.x * 32;

  const f32x4 zero = {0.f, 0.f, 0.f, 0.f};

  // ---------------- Phase 1: h1 = act(data @ W1 + b1) -> LDS ----------------
  {
    f32x4 acc[2][4];  // [tm][tn]
#pragma unroll
    for (int i = 0; i < 2; ++i)
#pragma unroll
      for (int j = 0; j < 4; ++j) acc[i][j] = zero;

#pragma unroll
    for (int kt = 0; kt < 8; ++kt) {
      const int k = kt * 32 + kq;
      f16x8 ah[2], al[2];
#pragma unroll
      for (int tm = 0; tm < 2; ++tm) {
        const float* pa = data + (size_t)(row0 + tm * 16 + m16) * 256 + k;
        const f32x4 x0 = *(const f32x4*)pa;
        const f32x4 x1 = *(const f32x4*)(pa + 4);
#pragma unroll
        for (int j = 0; j < 4; ++j) {
          const _Float16 g0 = (_Float16)x0[j];
          ah[tm][j] = g0;
          al[tm][j] = (_Float16)(x0[j] - (float)g0);
          const _Float16 g1 = (_Float16)x1[j];
          ah[tm][4 + j] = g1;
          al[tm][4 + j] = (_Float16)(x1[j] - (float)g1);
        }
      }
#pragma unroll
      for (int tn = 0; tn < 4; ++tn) {
        const int col = wv * 64 + tn * 16 + m16;
        const f16x8 bh = *(const f16x8*)(w1h + col * 256 + k);
        const f16x8 bl = *(const f16x8*)(w1l + col * 256 + k);
#pragma unroll
        for (int tm = 0; tm < 2; ++tm)
          acc[tm][tn] = mfma3(ah[tm], al[tm], bh, bl, acc[tm][tn]);
      }
    }
    // epilogue: bias+act, split to fp16 hi/lo, swizzled LDS write
#pragma unroll
    for (int tn = 0; tn < 4; ++tn) {
      const int col = wv * 64 + tn * 16 + m16;
      const float bs = b1[col];
      const float q0 = p1[col * 5 + 0], q1 = p1[col * 5 + 1],
                  q2 = p1[col * 5 + 2], q3 = p1[col * 5 + 3],
                  q4 = p1[col * 5 + 4];
#pragma unroll
      for (int tm = 0; tm < 2; ++tm) {
#pragma unroll
        for (int r = 0; r < 4; ++r) {
          const int row = tm * 16 + quad * 4 + r;
          const float y = act_f(acc[tm][tn][r] + bs, q0, q1, q2, q3, q4);
          const _Float16 h = (_Float16)y;
          const _Float16 l = (_Float16)(y - (float)h);
          const int off = ((row << 10) + (col << 1)) ^ ((row & 7) << 4);
          *(_Float16*)(smem + off) = h;
          *(_Float16*)(smem + 32768 + off) = l;
        }
      }
    }
  }
  __syncthreads();

  // ------ Phase 2: h2 = act(h1 @ W2 + b2), kt-outer over all 4 panels ------
  f32x4 acc2[4][2];  // [panel][tm]
#pragma unroll
  for (int i = 0; i < 4; ++i)
#pragma unroll
    for (int j = 0; j < 2; ++j) acc2[i][j] = zero;

  const int c2 = wv * 16 + m16;  // within-panel column owned by this thread

#pragma unroll 2
  for (int kt = 0; kt < 16; ++kt) {
    const int k = kt * 32 + kq;
    f16x8 ah[2], al[2];
#pragma unroll
    for (int tm = 0; tm < 2; ++tm) {
      // row = tm*16+m16 -> row&7 == m16&7
      const int off = (((tm * 16 + m16) << 10) + (k << 1)) ^ ((m16 & 7) << 4);
      ah[tm] = *(const f16x8*)(smem + off);
      al[tm] = *(const f16x8*)(smem + 32768 + off);
    }
#pragma unroll
    for (int p = 0; p < 4; ++p) {
      const size_t o = (size_t)(p * 128 + c2) * 512 + k;
      const f16x8 bh = *(const f16x8*)(w2h + o);
      const f16x8 bl = *(const f16x8*)(w2l + o);
#pragma unroll
      for (int tm = 0; tm < 2; ++tm)
        acc2[p][tm] = mfma3(ah[tm], al[tm], bh, bl, acc2[p][tm]);
    }
  }

  // activation params (issue before barrier; latency hides in the wait)
  float bs2[4], q0[4], q1[4], q2[4], q3[4], q4[4];
#pragma unroll
  for (int p = 0; p < 4; ++p) {
    const int colg = p * 128 + c2;
    bs2[p] = b2[colg];
    q0[p] = p2[colg * 5 + 0];
    q1[p] = p2[colg * 5 + 1];
    q2[p] = p2[colg * 5 + 2];
    q3[p] = p2[colg * 5 + 3];
    q4[p] = p2[colg * 5 + 4];
  }
  __syncthreads();  // all reads of h1 complete; region A reusable

  // epilogue: write full h2 (hi/lo, swizzled) over region A
#pragma unroll
  for (int p = 0; p < 4; ++p) {
    const int col = p * 128 + c2;
#pragma unroll
    for (int tm = 0; tm < 2; ++tm) {
#pragma unroll
      for (int r = 0; r < 4; ++r) {
        const int row = tm * 16 + quad * 4 + r;
        const float y =
            act_f(acc2[p][tm][r] + bs2[p], q0[p], q1[p], q2[p], q3[p], q4[p]);
        const _Float16 h = (_Float16)y;
        const _Float16 l = (_Float16)(y - (float)h);
        const int off = ((row << 10) + (col << 1)) ^ ((row & 7) << 4);
        *(_Float16*)(smem + off) = h;
        *(_Float16*)(smem + 32768 + off) = l;
      }
    }
  }
  __syncthreads();  // h2 ready

  // ---------- Phase 3: out_pre = act(h2 @ W3 + b3), 1m x 8n, K=512 ---------
  // wave owns all 32 rows x cols [wv*32, wv*32+32)
  f32x4 acc3[2][2];  // [tm][tn]
#pragma unroll
  for (int i = 0; i < 2; ++i)
#pragma unroll
    for (int j = 0; j < 2; ++j) acc3[i][j] = zero;

#pragma unroll 2
  for (int kt = 0; kt < 16; ++kt) {
    const int k = kt * 32 + kq;
    f16x8 ch[2], cl[2];
#pragma unroll
    for (int tm = 0; tm < 2; ++tm) {
      const int off = (((tm * 16 + m16) << 10) + (k << 1)) ^ ((m16 & 7) << 4);
      ch[tm] = *(const f16x8*)(smem + off);
      cl[tm] = *(const f16x8*)(smem + 32768 + off);
    }
#pragma unroll
    for (int tn = 0; tn < 2; ++tn) {
      const int col = wv * 32 + tn * 16 + m16;
      const size_t o = (size_t)col * 512 + k;
      const f16x8 dh = *(const f16x8*)(w3h + o);
      const f16x8 dl = *(const f16x8*)(w3l + o);
#pragma unroll
      for (int tm = 0; tm < 2; ++tm)
        acc3[tm][tn] = mfma3(ch[tm], cl[tm], dh, dl, acc3[tm][tn]);
    }
  }

  // ---------------- fused softmax over 256 cols per row ----------------
  float y[2][2][4];  // [tm][tn][r]
  {
    float bs3[2], s0[2], s1[2], s2[2], s3[2], s4[2];
#pragma unroll
    for (int tn = 0; tn < 2; ++tn) {
      const int colg = wv * 32 + tn * 16 + m16;
      bs3[tn] = b3[colg];
      s0[tn] = p3[colg * 5 + 0];
      s1[tn] = p3[colg * 5 + 1];
      s2[tn] = p3[colg * 5 + 2];
      s3[tn] = p3[colg * 5 + 3];
      s4[tn] = p3[colg * 5 + 4];
    }
#pragma unroll
    for (int tn = 0; tn < 2; ++tn)
#pragma unroll
      for (int tm = 0; tm < 2; ++tm)
#pragma unroll
        for (int r = 0; r < 4; ++r)
          y[tm][tn][r] = act_f(acc3[tm][tn][r] + bs3[tn], s0[tn], s1[tn],
                               s2[tn], s3[tn], s4[tn]);
  }
  // per-(tm,r): max over 2 tn, then 16-lane (m16) butterfly
#pragma unroll
  for (int tm = 0; tm < 2; ++tm)
#pragma unroll
    for (int r = 0; r < 4; ++r) {
      float m = fmaxf(y[tm][0][r], y[tm][1][r]);
#pragma unroll
      for (int off = 1; off < 16; off <<= 1) m = fmaxf(m, __shfl_xor(m, off));
      if (m16 == 0) {
        const int rowl = tm * 16 + quad * 4 + r;
        red[wv * 32 + rowl] = m;
      }
    }
  __syncthreads();
  if (tid < 32) {
    float m = red[tid];
#pragma unroll
    for (int w = 1; w < 8; ++w) m = fmaxf(m, red[w * 32 + tid]);
    rowred[tid] = m;
  }
  __syncthreads();
#pragma unroll
  for (int tm = 0; tm < 2; ++tm)
#pragma unroll
    for (int r = 0; r < 4; ++r) {
      const int rowl = tm * 16 + quad * 4 + r;
      const float m = rowred[rowl];
      float s = 0.f;
#pragma unroll
      for (int tn = 0; tn < 2; ++tn) {
        const float e =
            __builtin_amdgcn_exp2f((y[tm][tn][r] - m) * 1.4426950408889634f);
        y[tm][tn][r] = e;
        s += e;
      }
#pragma unroll
      for (int off = 1; off < 16; off <<= 1) s += __shfl_xor(s, off);
      if (m16 == 0) red[wv * 32 + rowl] = s;
    }
  __syncthreads();
  if (tid < 32) {
    float s = red[tid];
#pragma unroll
    for (int w = 1; w < 8; ++w) s += red[w * 32 + tid];
    rowred[tid] = __builtin_amdgcn_rcpf(s);
  }
  __syncthreads();
#pragma unroll
  for (int tm = 0; tm < 2; ++tm)
#pragma unroll
    for (int r = 0; r < 4; ++r) {
      const int rowl = tm * 16 + quad * 4 + r;
      const float inv = rowred[rowl];
#pragma unroll
      for (int tn = 0; tn < 2; ++tn) {
        const int colg = wv * 32 + tn * 16 + m16;
        out[(size_t)(row0 + rowl) * 256 + colg] = y[tm][tn][r] * inv;
      }
    }
}

extern "C" void kernel_launch(void* const* d_in, const int* in_sizes, int n_in,
                              void* d_out, int out_size, void* d_ws,
                              size_t ws_size, hipStream_t stream) {
  const float* data = (const float*)d_in[0];
  const float* W1 = (const float*)d_in[1];
  const float* b1 = (const float*)d_in[2];
  const float* a1 = (const float*)d_in[3];
  const float* W2 = (const float*)d_in[4];
  const float* b2 = (const float*)d_in[5];
  const float* a2 = (const float*)d_in[6];
  const float* W3 = (const float*)d_in[7];
  const float* b3 = (const float*)d_in[8];
  const float* a3 = (const float*)d_in[9];

  char* ws = (char*)d_ws;
  const size_t KB = 1024;
  _Float16* w1h = (_Float16*)(ws + 0 * KB);    // [512][256]
  _Float16* w1l = (_Float16*)(ws + 256 * KB);
  _Float16* w2h = (_Float16*)(ws + 512 * KB);  // [512][512]
  _Float16* w2l = (_Float16*)(ws + 1024 * KB);
  _Float16* w3h = (_Float16*)(ws + 1536 * KB);  // [256][512]
  _Float16* w3l = (_Float16*)(ws + 1792 * KB);

  splitT_k<<<(256 * 512 + 255) / 256, 256, 0, stream>>>(W1, w1h, w1l, 256, 512);
  splitT_k<<<(512 * 512 + 255) / 256, 256, 0, stream>>>(W2, w2h, w2l, 512, 512);
  splitT_k<<<(512 * 256 + 255) / 256, 256, 0, stream>>>(W3, w3h, w3l, 512, 256);

  fused_mlp<<<BATCH / 32, 512, 0, stream>>>(data, w1h, w1l, w2h, w2l, w3h, w3l,
                                            b1, a1, b2, a2, b3, a3,
                                            (float*)d_out);
}

// Round 8
// 427.189 us; speedup vs baseline: 1.4942x; 1.4942x over previous
//
#include <hip/hip_runtime.h>

#define BATCH 65536

typedef float f32x4 __attribute__((ext_vector_type(4)));
typedef _Float16 f16x8 __attribute__((ext_vector_type(8)));

__device__ __forceinline__ void async_ld16(const void* g, void* l) {
  __builtin_amdgcn_global_load_lds(
      (const __attribute__((address_space(1))) void*)g,
      (__attribute__((address_space(3))) void*)l, 16, 0, 0);
}

__device__ __forceinline__ float act_f(float x, float a0, float a1, float a2,
                                       float a3, float a4) {
  float ax = fabsf(x);
  float e = __builtin_amdgcn_exp2f(ax * -2.8853900817779268f);
  float th = (1.0f - e) * __builtin_amdgcn_rcpf(1.0f + e);
  th = copysignf(th, x);
  float arg = fmaf(a1, x, a2);
  float rev = arg * 0.15915494309189535f;
  rev -= floorf(rev);
  float s = __builtin_amdgcn_sinf(rev);
  return fmaf(a3, x, fmaf(a0 * th, s, a4));
}

// split + transpose weights: W[K][N] fp32 -> Wt_hi/lo[N][K] fp16.
// i indexes the OUTPUT (n,k): writes coalesced, reads strided (reads are
// cache-absorbed; scattered 2B writes were 64x write-amplified).
__global__ __launch_bounds__(256) void splitT_k(const float* __restrict__ W,
                                                _Float16* __restrict__ hi,
                                                _Float16* __restrict__ lo,
                                                int K, int N) {
  const int i = blockIdx.x * 256 + threadIdx.x;
  if (i >= K * N) return;
  const int n = i / K, k = i % K;
  const float w = W[(size_t)k * N + n];
  const _Float16 h = (_Float16)w;
  hi[i] = h;
  lo[i] = (_Float16)(w - (float)h);
}

__device__ __forceinline__ f32x4 mfma3(f16x8 ah, f16x8 al, f16x8 bh, f16x8 bl,
                                       f32x4 c) {
  c = __builtin_amdgcn_mfma_f32_16x16x32_f16(ah, bh, c, 0, 0, 0);
  c = __builtin_amdgcn_mfma_f32_16x16x32_f16(ah, bl, c, 0, 0, 0);
  c = __builtin_amdgcn_mfma_f32_16x16x32_f16(al, bh, c, 0, 0, 0);
  return c;
}

// C = A @ B, block tile 64 rows x 256 cols, BK=32. A: fp32 [M][K] (AF32,
// LDS-staged then split in-register) or fp16 hi/lo planes [M][K]. B: Wt[N][K]
// fp16 hi/lo. 3-product compensation (Ahi*Bhi + Ahi*Blo + Alo*Bhi, fp32 acc).
// 4 waves as 2x2; wave tile 32x128 (2 m-tiles x 8 n-tiles).
// Epilogue: bias + activation; FINAL -> in-block softmax over the 256 cols
// (blocks are full-N, 64 complete rows) then fp32 out (stride 256); else
// hi/lo fp16 planes (stride N).
template <bool AF32, bool FINAL>
__global__ __launch_bounds__(256, 4) void gemm_act(
    const float* __restrict__ Af, const _Float16* __restrict__ Ahi,
    const _Float16* __restrict__ Alo, const _Float16* __restrict__ Bhi,
    const _Float16* __restrict__ Blo, const float* __restrict__ bias,
    const float* __restrict__ ap, _Float16* __restrict__ Chi,
    _Float16* __restrict__ Clo, float* __restrict__ Cout, int K, int N) {
  // sA: 8 KB = fp32 A tile 64x32 (AF32) or 2 fp16 planes 64x32 each
  // sB: 32 KB = 2 fp16 planes 256x32
  __shared__ __align__(16) _Float16 sA[4096];
  __shared__ __align__(16) _Float16 sB[16384];

  const int tid = threadIdx.x;
  const int wv = tid >> 6;
  const int lane = tid & 63;
  const int wm = wv >> 1, wn = wv & 1;
  const int m16 = lane & 15, quad = lane >> 4;
  const int col0 = blockIdx.x * 256;
  const int row0 = blockIdx.y * 64;

  f32x4 acc[2][8];
  const f32x4 zero = {0.f, 0.f, 0.f, 0.f};
#pragma unroll
  for (int i = 0; i < 2; ++i)
#pragma unroll
    for (int j = 0; j < 8; ++j) acc[i][j] = zero;

  const int nk = K >> 5;
  for (int kt = 0; kt < nk; ++kt) {
    const int k0 = kt << 5;
    // ---- stage A ----
    if (AF32) {
      // 8 chunks of 1KB (8 rows x 128B); wave stages chunks 2wv, 2wv+1
      float* sAf = (float*)sA;
#pragma unroll
      for (int t = 0; t < 2; ++t) {
        const int c = wv * 2 + t;
        const int r = c * 8 + (lane >> 3);
        const size_t ga = (size_t)(row0 + r) * K + k0 + (lane & 7) * 4;
        async_ld16(Af + ga, (void*)&sAf[c * 256]);
      }
    } else {
      // per plane: 4 chunks (16 rows x 64B); wave stages chunk wv of each
      const int r = wv * 16 + (lane >> 2);
      const size_t ga = (size_t)(row0 + r) * K + k0 + (lane & 3) * 8;
      async_ld16(Ahi + ga, (void*)&sA[wv * 512]);
      async_ld16(Alo + ga, (void*)&sA[2048 + wv * 512]);
    }
    // ---- stage B: per plane 16 chunks (16 cols x 64B); wave stages 4 ----
#pragma unroll
    for (int t = 0; t < 4; ++t) {
      const int c = wv * 4 + t;
      const int col = c * 16 + (lane >> 2);
      const size_t gb = (size_t)(col0 + col) * K + k0 + (lane & 3) * 8;
      async_ld16(Bhi + gb, (void*)&sB[c * 512]);
      async_ld16(Blo + gb, (void*)&sB[8192 + c * 512]);
    }
    __syncthreads();

    // ---- A fragments ----
    f16x8 ah[2], al[2];
#pragma unroll
    for (int tm = 0; tm < 2; ++tm) {
      const int arow = wm * 32 + tm * 16 + m16;
      if (AF32) {
        const float* pa = (const float*)sA + arow * 32 + quad * 8;
        const f32x4 x0 = *(const f32x4*)pa;
        const f32x4 x1 = *(const f32x4*)(pa + 4);
#pragma unroll
        for (int j = 0; j < 4; ++j) {
          const _Float16 h0 = (_Float16)x0[j];
          ah[tm][j] = h0;
          al[tm][j] = (_Float16)(x0[j] - (float)h0);
          const _Float16 h1 = (_Float16)x1[j];
          ah[tm][4 + j] = h1;
          al[tm][4 + j] = (_Float16)(x1[j] - (float)h1);
        }
      } else {
        ah[tm] = *(const f16x8*)&sA[arow * 32 + quad * 8];
        al[tm] = *(const f16x8*)&sA[2048 + arow * 32 + quad * 8];
      }
    }
    // ---- B fragments + MFMA, n-tiles streamed ----
#pragma unroll
    for (int tn = 0; tn < 8; ++tn) {
      const int bcol = wn * 128 + tn * 16 + m16;
      const f16x8 bh = *(const f16x8*)&sB[bcol * 32 + quad * 8];
      const f16x8 bl = *(const f16x8*)&sB[8192 + bcol * 32 + quad * 8];
#pragma unroll
      for (int tm = 0; tm < 2; ++tm)
        acc[tm][tn] = mfma3(ah[tm], al[tm], bh, bl, acc[tm][tn]);
    }
    __syncthreads();
  }

  // ---- epilogue: C/D layout col=lane&15, row=quad*4+reg ----
  if (FINAL) {
    // bias + activation in place, then in-block softmax over 256 cols.
    // sA is dead after the K-loop's final barrier -> reuse for reductions.
    float* const redf = (float*)sA;        // [2 wn][64 rows]
    float* const rowm = (float*)sA + 128;  // [64] row max
    float* const rowi = (float*)sA + 192;  // [64] row 1/sum
#pragma unroll
    for (int tn = 0; tn < 8; ++tn) {
      const int col = col0 + wn * 128 + tn * 16 + m16;
      const float bs = bias[col];
      const float p0 = ap[col * 5 + 0];
      const float p1 = ap[col * 5 + 1];
      const float p2 = ap[col * 5 + 2];
      const float p3 = ap[col * 5 + 3];
      const float p4 = ap[col * 5 + 4];
#pragma unroll
      for (int tm = 0; tm < 2; ++tm)
#pragma unroll
        for (int r = 0; r < 4; ++r)
          acc[tm][tn][r] = act_f(acc[tm][tn][r] + bs, p0, p1, p2, p3, p4);
    }
    // row max: over 8 tn in-thread, then 16-lane (m16) butterfly, then wn
#pragma unroll
    for (int tm = 0; tm < 2; ++tm)
#pragma unroll
      for (int r = 0; r < 4; ++r) {
        float m = acc[tm][0][r];
#pragma unroll
        for (int tn = 1; tn < 8; ++tn) m = fmaxf(m, acc[tm][tn][r]);
#pragma unroll
        for (int off = 1; off < 16; off <<= 1) m = fmaxf(m, __shfl_xor(m, off));
        if (m16 == 0) {
          const int rowl = wm * 32 + tm * 16 + quad * 4 + r;
          redf[wn * 64 + rowl] = m;
        }
      }
    __syncthreads();
    if (tid < 64) rowm[tid] = fmaxf(redf[tid], redf[64 + tid]);
    __syncthreads();
    // exp + row sum
#pragma unroll
    for (int tm = 0; tm < 2; ++tm)
#pragma unroll
      for (int r = 0; r < 4; ++r) {
        const int rowl = wm * 32 + tm * 16 + quad * 4 + r;
        const float m = rowm[rowl];
        float s = 0.f;
#pragma unroll
        for (int tn = 0; tn < 8; ++tn) {
          const float e = __builtin_amdgcn_exp2f((acc[tm][tn][r] - m) *
                                                 1.4426950408889634f);
          acc[tm][tn][r] = e;
          s += e;
        }
#pragma unroll
        for (int off = 1; off < 16; off <<= 1) s += __shfl_xor(s, off);
        if (m16 == 0) redf[wn * 64 + rowl] = s;
      }
    __syncthreads();
    if (tid < 64) rowi[tid] = __builtin_amdgcn_rcpf(redf[tid] + redf[64 + tid]);
    __syncthreads();
    // normalized store
#pragma unroll
    for (int tm = 0; tm < 2; ++tm)
#pragma unroll
      for (int r = 0; r < 4; ++r) {
        const int rowl = wm * 32 + tm * 16 + quad * 4 + r;
        const float inv = rowi[rowl];
#pragma unroll
        for (int tn = 0; tn < 8; ++tn) {
          const int col = col0 + wn * 128 + tn * 16 + m16;
          Cout[(size_t)(row0 + rowl) * 256 + col] = acc[tm][tn][r] * inv;
        }
      }
  } else {
#pragma unroll
    for (int tn = 0; tn < 8; ++tn) {
      const int col = col0 + wn * 128 + tn * 16 + m16;
      const float bs = bias[col];
      const float p0 = ap[col * 5 + 0];
      const float p1 = ap[col * 5 + 1];
      const float p2 = ap[col * 5 + 2];
      const float p3 = ap[col * 5 + 3];
      const float p4 = ap[col * 5 + 4];
#pragma unroll
      for (int tm = 0; tm < 2; ++tm) {
        const int row = row0 + wm * 32 + tm * 16 + quad * 4;
#pragma unroll
        for (int r = 0; r < 4; ++r) {
          const float y = act_f(acc[tm][tn][r] + bs, p0, p1, p2, p3, p4);
          const size_t o = (size_t)(row + r) * N + col;
          const _Float16 h = (_Float16)y;
          Chi[o] = h;
          Clo[o] = (_Float16)(y - (float)h);
        }
      }
    }
  }
}

extern "C" void kernel_launch(void* const* d_in, const int* in_sizes, int n_in,
                              void* d_out, int out_size, void* d_ws,
                              size_t ws_size, hipStream_t stream) {
  const float* data = (const float*)d_in[0];
  const float* W1 = (const float*)d_in[1];
  const float* b1 = (const float*)d_in[2];
  const float* a1 = (const float*)d_in[3];
  const float* W2 = (const float*)d_in[4];
  const float* b2 = (const float*)d_in[5];
  const float* a2 = (const float*)d_in[6];
  const float* W3 = (const float*)d_in[7];
  const float* b3 = (const float*)d_in[8];
  const float* a3 = (const float*)d_in[9];
  float* out = (float*)d_out;

  char* ws = (char*)d_ws;
  const size_t KB = 1024, MB = 1024 * 1024;
  _Float16* w1hi = (_Float16*)(ws + 0 * KB);  // Wt1[512][256]
  _Float16* w1lo = (_Float16*)(ws + 256 * KB);
  _Float16* w2hi = (_Float16*)(ws + 512 * KB);  // Wt2[512][512]
  _Float16* w2lo = (_Float16*)(ws + 1024 * KB);
  _Float16* w3hi = (_Float16*)(ws + 1536 * KB);  // Wt3[256][512]
  _Float16* w3lo = (_Float16*)(ws + 1792 * KB);
  // h1 hi/lo: 65536x512 fp16 = 64 MB each; h2lo 64 MB; h2hi lives in d_out
  // (row i of h2hi = bytes [1024i,1024i+1024) = row i of out; GEMM3 blocks
  // are full-N and row-disjoint, and the softmax-fused epilogue writes only
  // after the block's K-loop reads complete -> alias-safe)
  _Float16* h1hi = (_Float16*)(ws + 2 * MB);
  _Float16* h1lo = (_Float16*)(ws + 2 * MB + (size_t)BATCH * 512 * 2);
  _Float16* h2lo = (_Float16*)(ws + 2 * MB + (size_t)BATCH * 512 * 4);
  _Float16* h2hi = (_Float16*)d_out;

  splitT_k<<<(256 * 512 + 255) / 256, 256, 0, stream>>>(W1, w1hi, w1lo, 256, 512);
  splitT_k<<<(512 * 512 + 255) / 256, 256, 0, stream>>>(W2, w2hi, w2lo, 512, 512);
  splitT_k<<<(512 * 256 + 255) / 256, 256, 0, stream>>>(W3, w3hi, w3lo, 512, 256);

  // grid: x = N-tiles (fastest -> strip-mates dispatch-adjacent, L3-hot A),
  //       y = 64-row M-strips
  gemm_act<true, false><<<dim3(2, BATCH / 64), 256, 0, stream>>>(
      data, nullptr, nullptr, w1hi, w1lo, b1, a1, h1hi, h1lo, nullptr, 256, 512);
  gemm_act<false, false><<<dim3(2, BATCH / 64), 256, 0, stream>>>(
      nullptr, h1hi, h1lo, w2hi, w2lo, b2, a2, h2hi, h2lo, nullptr, 512, 512);
  gemm_act<false, true><<<dim3(1, BATCH / 64), 256, 0, stream>>>(
      nullptr, h2hi, h2lo, w3hi, w3lo, b3, a3, nullptr, nullptr, out, 512, 256);
}